// Round 21
// baseline (53.882 us; speedup 1.0000x reference)
//
#include <hip/hip_runtime.h>

#define NPIX 9216
#define PLANE 82944           // 288*288
#define WPL 230400            // floats per (o,i) weight plane
#define NOUT 995328           // 4*9*3*9216

typedef float f4v __attribute__((ext_vector_type(4)));

// ---- pass 1: one wave per (tile, og, i); partial sums via atomicAdd ----
__global__ __launch_bounds__(64)
void lfp1(const float* __restrict__ lf, const float* __restrict__ wts,
          float* __restrict__ out)
{
    __shared__ float ldsW[1344];          // 3oc*16px*28, 5.25 KB

    const int lane = threadIdx.x;
    const int px   = lane & 15;
    const int b    = lane >> 4;           // 0..3
    const int bid  = blockIdx.x;
    // chunked bijective XCD swizzle (15552 % 8 == 0): all 27 (og,i) of a tile
    // land on the same XCD -> patch rows L2-shared
    const int swz  = (bid & 7) * 1944 + (bid >> 3);
    const int tile = swz / 27;
    const int rem  = swz - tile * 27;
    const int og   = rem / 9;
    const int ii   = rem - og * 9;

    const int oh   = tile / 6;
    const int tc   = tile - oh * 6;
    const int g    = tile * 16 + px;
    const int ow   = tc * 16 + px;
    const int y0   = oh * 3 - 2;          // pt = pl = 2, no bottom/right pad
    const int x0   = ow * 3 - 2;
    const int xcl  = (x0 < 0) ? 0 : x0;
    const bool xneg = (x0 < 0);           // only px==0 in tc==0 blocks
    const bool tc0  = (tc == 0);          // block-uniform
    const bool oh0  = (oh == 0);          // block-uniform

    // ---- staging: 48 lanes own one (oc,px) row each; 25 floats/row ----
    const bool srow = (lane < 48);
    const int soc = lane >> 4;
    const int spx = lane & 15;
    const long swbase = (long)((og * 3 + soc) * 9 + ii) * WPL + tile * 400 + spx * 25;
    float* const swdst = ldsW + soc * 448 + spx * 28;

    if (srow) {
        const float* gp = wts + swbase;
        f4v r0, r1, r2, r3, r4, r5; float r6;
        __builtin_memcpy(&r0, gp,      16);
        __builtin_memcpy(&r1, gp + 4,  16);
        __builtin_memcpy(&r2, gp + 8,  16);
        __builtin_memcpy(&r3, gp + 12, 16);
        __builtin_memcpy(&r4, gp + 16, 16);
        __builtin_memcpy(&r5, gp + 20, 16);
        r6 = gp[24];
        *(f4v*)(swdst +  0) = r0;
        *(f4v*)(swdst +  4) = r1;
        *(f4v*)(swdst +  8) = r2;
        *(f4v*)(swdst + 12) = r3;
        *(f4v*)(swdst + 16) = r4;
        *(f4v*)(swdst + 20) = r5;
        swdst[24] = r6;
    }
    // single-wave block: DS in-order, no barrier needed

    auto loadP = [&](f4v (&A)[5], float (&E)[5], int c) {
        const float* rb = lf + ((b * 9 + ii) * 3 + c) * PLANE + xcl;
        #pragma unroll
        for (int kh = 0; kh < 5; ++kh) {
            const int y = y0 + kh;
            if (!oh0 || y >= 0) {             // block-uniform
                const float* rp = rb + y * 288;
                __builtin_memcpy(&A[kh], rp, 16);
                E[kh] = rp[4];                // x0+4 <= 287: in-bounds
            } else { A[kh] = (f4v)0.f; E[kh] = 0.f; }
        }
    };

    float wk[3][25];
    float acc[3][3] = {{0,0,0},{0,0,0},{0,0,0}};

    auto doFMA = [&](const f4v (&A)[5], const float (&E)[5], int c) {
        #pragma unroll
        for (int kh = 0; kh < 5; ++kh) {
            const f4v a = A[kh]; const float e = E[kh];
            float q0,q1,q2,q3,q4;
            if (tc0) {
                q0 = xneg ? 0.f : a.x;  q1 = xneg ? 0.f : a.y;
                q2 = xneg ? a.x : a.z;  q3 = xneg ? a.y : a.w;
                q4 = xneg ? a.z : e;
            } else { q0=a.x; q1=a.y; q2=a.z; q3=a.w; q4=e; }
            #pragma unroll
            for (int oc = 0; oc < 3; ++oc) {
                acc[oc][c] = fmaf(wk[oc][kh*5+0], q0, acc[oc][c]);
                acc[oc][c] = fmaf(wk[oc][kh*5+1], q1, acc[oc][c]);
                acc[oc][c] = fmaf(wk[oc][kh*5+2], q2, acc[oc][c]);
                acc[oc][c] = fmaf(wk[oc][kh*5+3], q3, acc[oc][c]);
                acc[oc][c] = fmaf(wk[oc][kh*5+4], q4, acc[oc][c]);
            }
        }
    };

    f4v PA[5], PB[5]; float EA[5], EB[5];
    loadP(PA, EA, 0);

    // weights -> 75 regs: 6x ds_read_b128 + 1x b32 per oc
    #pragma unroll
    for (int oc = 0; oc < 3; ++oc) {
        const float* wr = ldsW + oc * 448 + px * 28;    // 112B-aligned
        const f4v* wq = (const f4v*)wr;
        const f4v u0=wq[0], u1=wq[1], u2=wq[2], u3=wq[3], u4=wq[4], u5=wq[5];
        wk[oc][0]=u0.x;  wk[oc][1]=u0.y;  wk[oc][2]=u0.z;  wk[oc][3]=u0.w;
        wk[oc][4]=u1.x;  wk[oc][5]=u1.y;  wk[oc][6]=u1.z;  wk[oc][7]=u1.w;
        wk[oc][8]=u2.x;  wk[oc][9]=u2.y;  wk[oc][10]=u2.z; wk[oc][11]=u2.w;
        wk[oc][12]=u3.x; wk[oc][13]=u3.y; wk[oc][14]=u3.z; wk[oc][15]=u3.w;
        wk[oc][16]=u4.x; wk[oc][17]=u4.y; wk[oc][18]=u4.z; wk[oc][19]=u4.w;
        wk[oc][20]=u5.x; wk[oc][21]=u5.y; wk[oc][22]=u5.z; wk[oc][23]=u5.w;
        wk[oc][24]=wr[24];
    }

    loadP(PB, EB, 1);        // c=1 in flight under c=0 FMAs
    doFMA(PA, EA, 0);
    loadP(PA, EA, 2);        // c=2 in flight under c=1 FMAs
    doFMA(PB, EB, 1);
    doFMA(PA, EA, 2);

    // ---- partial-sum epilogue: 9 atomicAdds, all-distinct addresses ----
    #pragma unroll
    for (int oc = 0; oc < 3; ++oc) {
        const int o = og * 3 + oc;
        #pragma unroll
        for (int c = 0; c < 3; ++c)
            atomicAdd(&out[((b * 9 + o) * 3 + c) * NPIX + g], acc[oc][c]);
    }
}

// ---- pass 2: bias + clip, in place ----
__global__ __launch_bounds__(256)
void lfp2(float* __restrict__ out, const float* __restrict__ bias)
{
    const int idx4 = blockIdx.x * 256 + threadIdx.x;   // 972*256 = 248832 float4s
    const int f = idx4 * 4;
    const int row = f / NPIX;                          // same row for all 4 floats
    const int g = f - row * NPIX;
    const int o = (row / 3) % 9;
    f4v v, bv;
    __builtin_memcpy(&v,  &out[f], 16);
    __builtin_memcpy(&bv, &bias[o * NPIX + g], 16);
    #pragma unroll
    for (int q = 0; q < 4; ++q) {
        float t = v[q] + bv[q];
        v[q] = fminf(fmaxf(t, 0.f), 1.f);
    }
    *(f4v*)&out[f] = v;
}

extern "C" void kernel_launch(void* const* d_in, const int* in_sizes, int n_in,
                              void* d_out, int out_size, void* d_ws, size_t ws_size,
                              hipStream_t stream) {
    const float* lf   = (const float*)d_in[0];
    const float* wts  = (const float*)d_in[1];
    const float* bias = (const float*)d_in[2];
    float* out = (float*)d_out;
    (void)d_ws; (void)ws_size; (void)in_sizes; (void)n_in; (void)out_size;

    hipMemsetAsync(out, 0, (size_t)NOUT * sizeof(float), stream);
    lfp1<<<dim3(576 * 27), dim3(64), 0, stream>>>(lf, wts, out);   // 15552 waves
    lfp2<<<dim3(972), dim3(256), 0, stream>>>(out, bias);
}

// Round 22
// 32.598 us; speedup vs baseline: 1.6529x; 1.6529x over previous
//
#include <hip/hip_runtime.h>

#define NPIX 9216
#define PLANE 82944           // 288*288
#define WPL 230400            // floats per (o,i) weight plane

typedef float f4v __attribute__((ext_vector_type(4)));

// R20 structure: best known (32.6 us). Block = 2 waves (i-split 5/4), per-wave
// private single-buffered padded weight LDS, row-aligned staging, direct-global
// patches, c-rotating register double-buffer, zero main-loop barriers.
// DO NOT add a min-waves launch_bounds clause (R3/R17: VGPR clamp -> spill).
__global__ __launch_bounds__(128)
void lfk22(const float* __restrict__ lf, const float* __restrict__ wts,
           const float* __restrict__ bias, float* __restrict__ out)
{
    __shared__ float ldsW[2][1344];       // 10.75 KB

    const int tid  = threadIdx.x;
    const int wv   = tid >> 6;            // i-split wave 0..1 (i 0-4 / 5-8)
    const int lane = tid & 63;
    const int px   = lane & 15;
    const int b    = lane >> 4;           // 0..3
    const int bid  = blockIdx.x;
    const int swz  = (bid & 7) * 216 + (bid >> 3);   // bijective XCD swizzle
    const int tile = swz / 3;
    const int og   = swz - tile * 3;
    const int oh   = tile / 6;
    const int tc   = tile - oh * 6;
    const int g    = tile * 16 + px;
    const int ow   = tc * 16 + px;
    const int y0   = oh * 3 - 2;          // pt = pl = 2, no bottom/right pad
    const int x0   = ow * 3 - 2;
    const int xcl  = (x0 < 0) ? 0 : x0;
    const bool xneg = (x0 < 0);           // only px==0 in tc==0 blocks
    const bool tc0  = (tc == 0);          // block-uniform
    const bool oh0  = (oh == 0);          // block-uniform

    float* const myl = &ldsW[wv][0];
    const int i0 = wv ? 5 : 0;            // wave0: i=0..4, wave1: i=5..8
    const int i1 = wv ? 9 : 5;

    // ---- staging: 48 lanes own one (oc,px) row each; 25 floats/row ----
    const bool srow = (lane < 48);
    const int soc = lane >> 4;            // 0..2 (valid when srow)
    const int spx = lane & 15;
    const long swbase = (long)((og * 3 + soc) * 9) * WPL + tile * 400 + spx * 25;
    float* const swdst = myl + soc * 448 + spx * 28;

    f4v r0, r1, r2, r3, r4, r5; float r6;
    auto stageLoad = [&](int i) {
        if (srow) {
            const float* gp = wts + swbase + (long)i * WPL;
            __builtin_memcpy(&r0, gp,      16);
            __builtin_memcpy(&r1, gp + 4,  16);
            __builtin_memcpy(&r2, gp + 8,  16);
            __builtin_memcpy(&r3, gp + 12, 16);
            __builtin_memcpy(&r4, gp + 16, 16);
            __builtin_memcpy(&r5, gp + 20, 16);
            r6 = gp[24];
        }
    };
    auto scatterWrite = [&]() {
        if (srow) {                       // 6x ds_write_b128 + 1x b32
            *(f4v*)(swdst +  0) = r0;
            *(f4v*)(swdst +  4) = r1;
            *(f4v*)(swdst +  8) = r2;
            *(f4v*)(swdst + 12) = r3;
            *(f4v*)(swdst + 16) = r4;
            *(f4v*)(swdst + 20) = r5;
            swdst[24] = r6;
        }
    };

    // ---- patch load: one c at a time into a named 25-float set ----
    auto loadP = [&](f4v (&A)[5], float (&E)[5], int i, int c) {
        const float* rb = lf + ((b * 9 + i) * 3 + c) * PLANE + xcl;
        #pragma unroll
        for (int kh = 0; kh < 5; ++kh) {
            const int y = y0 + kh;
            if (!oh0 || y >= 0) {             // block-uniform
                const float* rp = rb + y * 288;
                __builtin_memcpy(&A[kh], rp, 16);
                E[kh] = rp[4];                // x0+4 <= 287: in-bounds
            } else { A[kh] = (f4v)0.f; E[kh] = 0.f; }
        }
    };

    float wk[3][25];                      // weights resident per i-step
    float acc[3][3] = {{0,0,0},{0,0,0},{0,0,0}};

    auto doFMA = [&](const f4v (&A)[5], const float (&E)[5], int c) {
        #pragma unroll
        for (int kh = 0; kh < 5; ++kh) {
            const f4v a = A[kh]; const float e = E[kh];
            float q0,q1,q2,q3,q4;
            if (tc0) {
                q0 = xneg ? 0.f : a.x;  q1 = xneg ? 0.f : a.y;
                q2 = xneg ? a.x : a.z;  q3 = xneg ? a.y : a.w;
                q4 = xneg ? a.z : e;
            } else { q0=a.x; q1=a.y; q2=a.z; q3=a.w; q4=e; }
            #pragma unroll
            for (int oc = 0; oc < 3; ++oc) {
                acc[oc][c] = fmaf(wk[oc][kh*5+0], q0, acc[oc][c]);
                acc[oc][c] = fmaf(wk[oc][kh*5+1], q1, acc[oc][c]);
                acc[oc][c] = fmaf(wk[oc][kh*5+2], q2, acc[oc][c]);
                acc[oc][c] = fmaf(wk[oc][kh*5+3], q3, acc[oc][c]);
                acc[oc][c] = fmaf(wk[oc][kh*5+4], q4, acc[oc][c]);
            }
        }
    };

    f4v PA[5], PB[5]; float EA[5], EB[5];

    // ---- prologue ----
    stageLoad(i0);
    scatterWrite();
    loadP(PA, EA, i0, 0);

    #pragma unroll 1
    for (int i = i0; i < i1; ++i) {
        const bool more = (i < i1 - 1);

        // weights(i) -> 75 regs: 6x ds_read_b128 + 1x b32 per oc
        #pragma unroll
        for (int oc = 0; oc < 3; ++oc) {
            const float* wr = myl + oc * 448 + px * 28;   // 112B-aligned
            const f4v* wq = (const f4v*)wr;
            const f4v u0=wq[0], u1=wq[1], u2=wq[2], u3=wq[3], u4=wq[4], u5=wq[5];
            wk[oc][0]=u0.x;  wk[oc][1]=u0.y;  wk[oc][2]=u0.z;  wk[oc][3]=u0.w;
            wk[oc][4]=u1.x;  wk[oc][5]=u1.y;  wk[oc][6]=u1.z;  wk[oc][7]=u1.w;
            wk[oc][8]=u2.x;  wk[oc][9]=u2.y;  wk[oc][10]=u2.z; wk[oc][11]=u2.w;
            wk[oc][12]=u3.x; wk[oc][13]=u3.y; wk[oc][14]=u3.z; wk[oc][15]=u3.w;
            wk[oc][16]=u4.x; wk[oc][17]=u4.y; wk[oc][18]=u4.z; wk[oc][19]=u4.w;
            wk[oc][20]=u5.x; wk[oc][21]=u5.y; wk[oc][22]=u5.z; wk[oc][23]=u5.w;
            wk[oc][24]=wr[24];
        }

        if (more) stageLoad(i + 1);     // issue EARLY: ~225 FMAs of latency cover

        loadP(PB, EB, i, 1);            // c=1 in flight under c=0 FMAs
        doFMA(PA, EA, 0);
        loadP(PA, EA, i, 2);            // c=2 in flight under c=1 FMAs
        doFMA(PB, EB, 1);
        doFMA(PA, EA, 2);

        if (more) {
            scatterWrite();             // single private buffer: in-order DS = safe
            loadP(PA, EA, i + 1, 0);    // first c of next step in flight
        }
    }

    // ---- cross-wave reduction (single barrier) ----
    if (wv != 0) {
        #pragma unroll
        for (int oc = 0; oc < 3; ++oc)
            #pragma unroll
            for (int c = 0; c < 3; ++c)
                myl[lane * 9 + oc * 3 + c] = acc[oc][c];
    }
    __syncthreads();

    if (wv == 0) {
        #pragma unroll
        for (int oc = 0; oc < 3; ++oc)
            #pragma unroll
            for (int c = 0; c < 3; ++c)
                acc[oc][c] += ldsW[1][lane * 9 + oc * 3 + c];
        #pragma unroll
        for (int oc = 0; oc < 3; ++oc) {
            const int o = og * 3 + oc;
            const float bo = bias[o * NPIX + g];
            #pragma unroll
            for (int c = 0; c < 3; ++c) {
                float v = acc[oc][c] + bo;
                v = fminf(fmaxf(v, 0.f), 1.f);
                out[((b * 9 + o) * 3 + c) * NPIX + g] = v;
            }
        }
    }
}

extern "C" void kernel_launch(void* const* d_in, const int* in_sizes, int n_in,
                              void* d_out, int out_size, void* d_ws, size_t ws_size,
                              hipStream_t stream) {
    const float* lf   = (const float*)d_in[0];
    const float* wts  = (const float*)d_in[1];
    const float* bias = (const float*)d_in[2];
    float* out = (float*)d_out;
    (void)d_ws; (void)ws_size; (void)in_sizes; (void)n_in; (void)out_size;

    dim3 grid(576 * 3);     // 1728 blocks x 2 waves = 3456 waves: fully co-resident
    dim3 block(128);
    lfk22<<<grid, block, 0, stream>>>(lf, wts, bias, out);
}